// Round 12
// baseline (635.346 us; speedup 1.0000x reference)
//
#include <hip/hip_runtime.h>

#define NUQ 100000
#define NIQ 100000
#define NHN 200000
#define CC 128
#define PDM 64
#define PHM 128
#define EHET 500000
#define EHOM 1000000
#define SCAN_CHUNK 2048

typedef __attribute__((ext_vector_type(8))) short bf16x8;
typedef __attribute__((ext_vector_type(4))) float f32x4;

__device__ inline unsigned short f2bf(float x) {
  union { float f; unsigned u; } c; c.f = x;
  unsigned r = c.u + 0x7FFF + ((c.u >> 16) & 1);
  return (unsigned short)(r >> 16);
}
__device__ inline float bflo(unsigned u) { union { unsigned u; float f; } c; c.u = u << 16; return c.f; }
__device__ inline float bfhi(unsigned u) { union { unsigned u; float f; } c; c.u = u & 0xffff0000u; return c.f; }

// ---------- fused: degree counts (het both dirs + hom) + PE->bf16 convert ----------
__global__ void k_setup2(const int* __restrict__ eui_dst, const int* __restrict__ eiu_dst,
                         const int* __restrict__ ehom_dst,
                         const float* __restrict__ pe, unsigned* __restrict__ pe_bf_out,
                         int* __restrict__ cnt, int* __restrict__ cnt_hom) {
  int i = blockIdx.x * 256 + threadIdx.x;
  const int EA = 2 * EHET + EHOM;
  if (i < EHET) {
    atomicAdd(&cnt[NUQ + eui_dst[i]], 1);
  } else if (i < 2 * EHET) {
    atomicAdd(&cnt[eiu_dst[i - EHET]], 1);
  } else if (i < EA) {
    atomicAdd(&cnt_hom[ehom_dst[i - 2 * EHET]], 1);
  } else if (i < EA + NHN * PDM / 2) {
    int j = i - EA;
    float2 v = *reinterpret_cast<const float2*>(&pe[(size_t)j * 2]);
    pe_bf_out[j] = (unsigned)f2bf(v.x) | ((unsigned)f2bf(v.y) << 16);
  }
}

// ---------- fused 3-segment exclusive scan ----------
#define NB0 49
#define NB1 49
#define NB2 98
__global__ __launch_bounds__(256) void k_scan1f(const int* __restrict__ cnt, const int* __restrict__ cnt_hom,
                                                int* __restrict__ off_iu, int* __restrict__ off_ui,
                                                int* __restrict__ off_hom, int* __restrict__ blksum) {
  const int* in; int n; int* out; int* bs; int b;
  int blk = blockIdx.x;
  if (blk < NB0)            { in = cnt;       n = NUQ; out = off_iu;  bs = blksum;       b = blk; }
  else if (blk < NB0 + NB1) { in = cnt + NUQ; n = NIQ; out = off_ui;  bs = blksum + 256; b = blk - NB0; }
  else                      { in = cnt_hom;   n = NHN; out = off_hom; bs = blksum + 512; b = blk - NB0 - NB1; }
  __shared__ int sh[256];
  int t = threadIdx.x;
  int base = b * SCAN_CHUNK + t * 8;
  int v[8]; int s = 0;
#pragma unroll
  for (int i = 0; i < 8; ++i) {
    int x = (base + i < n) ? in[base + i] : 0;
    v[i] = s;
    s += x;
  }
  sh[t] = s; __syncthreads();
  for (int d = 1; d < 256; d <<= 1) {
    int x = (t >= d) ? sh[t - d] : 0;
    __syncthreads();
    sh[t] += x;
    __syncthreads();
  }
  int texcl = sh[t] - s;
#pragma unroll
  for (int i = 0; i < 8; ++i)
    if (base + i < n) out[base + i] = texcl + v[i];
  if (t == 255) bs[b] = sh[255];
}

__global__ void k_scan2f(const int* __restrict__ blksum, int* __restrict__ blkoff) {
  int seg = blockIdx.x;
  int nb = (seg == 2) ? NB2 : NB0;
  const int* bs = blksum + seg * 256;
  int* bo = blkoff + seg * 257;
  __shared__ int sh[256];
  int t = threadIdx.x;
  int x0 = (t < nb) ? bs[t] : 0;
  sh[t] = x0; __syncthreads();
  for (int d = 1; d < 256; d <<= 1) {
    int x = (t >= d) ? sh[t - d] : 0;
    __syncthreads();
    sh[t] += x;
    __syncthreads();
  }
  if (t < nb) bo[t] = sh[t] - x0;
  if (t == 0) bo[nb] = sh[255];
}

#define G0 392
#define G2 784
__global__ void k_scan3f(int* __restrict__ off_iu, int* __restrict__ off_ui, int* __restrict__ off_hom,
                         const int* __restrict__ blkoff) {
  int blk = blockIdx.x;
  int* off; int n; const int* bo; int nb; int b;
  if (blk < G0)           { off = off_iu;  n = NUQ; bo = blkoff;       nb = NB0; b = blk; }
  else if (blk < 2 * G0)  { off = off_ui;  n = NIQ; bo = blkoff + 257; nb = NB1; b = blk - G0; }
  else                    { off = off_hom; n = NHN; bo = blkoff + 514; nb = NB2; b = blk - 2 * G0; }
  int i = b * 256 + threadIdx.x;
  if (i < n) off[i] += bo[i >> 11];
  else if (i == n) off[n] = bo[nb];
}

// ---------- single fused weight-prepack helper ----------
__device__ inline void pack_one(const float* W, int i, int NC, int kkBase, int KKtot,
                                unsigned short* out) {
  int k = i / NC, n = i % NC;
  int kk = kkBase + (k >> 5);
  int lane = (n & 15) + (((k >> 3) & 3) << 4);
  int j8 = k & 7;
  int o16 = ((n >> 4) * KKtot + kk) * 64 + lane;
  out[o16 * 8 + j8] = f2bf(W[i]);
}

// ---------- fused: CSR fill (atomic cursor) + weight prepack ----------
#define FILLB 7813   // ceil(2*EHET+EHOM / 256)
__global__ __launch_bounds__(256) void k_fillpack(
    const int* __restrict__ edge_ui, const int* __restrict__ edge_iu,
    const int* __restrict__ edge_hom,
    const int* __restrict__ off_ui, const int* __restrict__ off_iu,
    const int* __restrict__ off_hom,
    int* __restrict__ cur_i, int* __restrict__ cur_u, int* __restrict__ cur_h,
    int* __restrict__ idx_ui, int* __restrict__ idx_iu, int* __restrict__ idx_hom,
    const float* __restrict__ siu_Wl, const float* __restrict__ siu_Wr,
    const float* __restrict__ sui_Wl, const float* __restrict__ sui_Wr,
    const float* __restrict__ pe_W, const float* __restrict__ phi_W1, const float* __restrict__ phi_W2,
    unsigned short* __restrict__ sageP, unsigned short* __restrict__ peP,
    unsigned short* __restrict__ g1P, unsigned short* __restrict__ g2P) {
  int blk = blockIdx.x;
  if (blk < FILLB) {
    int gid = blk * 256 + threadIdx.x;
    if (gid < EHET) {
      int d = edge_ui[EHET + gid];
      int p = atomicAdd(&cur_i[d], 1);
      idx_ui[off_ui[d] + p] = edge_ui[gid];
    } else if (gid < 2 * EHET) {
      int e = gid - EHET;
      int d = edge_iu[EHET + e];
      int p = atomicAdd(&cur_u[d], 1);
      idx_iu[off_iu[d] + p] = edge_iu[e];
    } else if (gid < 2 * EHET + EHOM) {
      int e = gid - 2 * EHET;
      int d = edge_hom[EHOM + e];
      int p = atomicAdd(&cur_h[d], 1);
      idx_hom[off_hom[d] + p] = edge_hom[e];
    }
    return;
  }
  int pb = blk - FILLB;
  int seg = pb / 96;
  int i = (pb % 96) * 256 + threadIdx.x;
  int l = seg / 7, j = seg % 7;
  switch (j) {
    case 0: if (i < CC * 128) pack_one(siu_Wl + (size_t)l * CC * CC, i, 128, 0, 8, sageP + (size_t)(l * 2) * 32768); break;
    case 1: if (i < CC * 128) pack_one(siu_Wr + (size_t)l * CC * CC, i, 128, 4, 8, sageP + (size_t)(l * 2) * 32768); break;
    case 2: if (i < CC * 128) pack_one(sui_Wl + (size_t)l * CC * CC, i, 128, 0, 8, sageP + (size_t)(l * 2 + 1) * 32768); break;
    case 3: if (i < CC * 128) pack_one(sui_Wr + (size_t)l * CC * CC, i, 128, 4, 8, sageP + (size_t)(l * 2 + 1) * 32768); break;
    case 4: if (i < (CC + PDM) * 128) pack_one(pe_W + (size_t)l * (CC + PDM) * CC, i, 128, 0, 6, peP + (size_t)l * 24576); break;
    case 5: if (i < PDM * 128) pack_one(phi_W1 + (size_t)l * PDM * PHM, i, 128, 0, 2, g1P + (size_t)l * 8192); break;
    case 6: if (i < PHM * 64) pack_one(phi_W2 + (size_t)l * PHM * PDM, i, 64, 0, 4, g2P + (size_t)l * 8192); break;
  }
}

// ---------- fused GIN: CSR gather (clamped unroll-8) + MLP MFMA, BOTH layers ----------
__global__ __launch_bounds__(256) void k_gin2(
    const float* __restrict__ pe,
    const int* __restrict__ off, const int* __restrict__ idx,
    const unsigned short* __restrict__ pe_bf,
    const unsigned short* __restrict__ g1P, const float* __restrict__ phi_b1,
    const unsigned short* __restrict__ g2P, const float* __restrict__ phi_b2,
    const float* __restrict__ eps_p,
    unsigned short* __restrict__ pel0, unsigned short* __restrict__ pel1) {
  __shared__ __align__(16) char Ah[32 * 128];
  __shared__ __align__(16) char Hh[32 * 256];
  int t = threadIdx.x, wave = t >> 6, lane = t & 63;
  int row0 = blockIdx.x * 32;
  int half = lane >> 5, hl = lane & 31;
  int rt = wave & 1, ctb = (wave >> 1) * 4;
  int arow = rt * 16 + (lane & 15);
  int axor = arow & 7;
  float sg0[4], sg1[4], ps0[4], ps1[4];
#pragma unroll
  for (int pr = 0; pr < 4; ++pr) {
    int r = wave * 8 + pr * 2 + half;
    int n = row0 + r;
    int e0 = off[n], e1 = off[n + 1];
    float s0 = 0.f, s1 = 0.f, t0 = 0.f, t1 = 0.f;
    int e = e0;
    for (; e + 2 <= e1; e += 2) {
      unsigned u0 = *reinterpret_cast<const unsigned*>(&pe_bf[(size_t)idx[e] * PDM + hl * 2]);
      unsigned u1 = *reinterpret_cast<const unsigned*>(&pe_bf[(size_t)idx[e + 1] * PDM + hl * 2]);
      s0 += bflo(u0); s1 += bfhi(u0);
      t0 += bflo(u1); t1 += bfhi(u1);
    }
    if (e < e1) {
      unsigned u0 = *reinterpret_cast<const unsigned*>(&pe_bf[(size_t)idx[e] * PDM + hl * 2]);
      s0 += bflo(u0); s1 += bfhi(u0);
    }
    sg0[pr] = s0 + t0; sg1[pr] = s1 + t1;
    float2 p2 = *reinterpret_cast<const float2*>(&pe[(size_t)n * PDM + hl * 2]);
    ps0[pr] = p2.x; ps1[pr] = p2.y;
  }
#pragma unroll
  for (int l = 0; l < 2; ++l) {
    const unsigned short* B1p = g1P + (size_t)l * 8192;
    const unsigned short* B2p = g2P + (size_t)l * 8192;
    const float* b1 = phi_b1 + (size_t)l * PHM;
    const float* b2 = phi_b2 + (size_t)l * PDM;
    unsigned short* pel = l ? pel1 : pel0;
    float e1v = 1.0f + eps_p[l];
#pragma unroll
    for (int pr = 0; pr < 4; ++pr) {
      int r = wave * 8 + pr * 2 + half;
      unsigned pv = (unsigned)f2bf(e1v * ps0[pr] + sg0[pr]) |
                    ((unsigned)f2bf(e1v * ps1[pr] + sg1[pr]) << 16);
      int chunk = (hl >> 2) ^ (r & 7);
      *reinterpret_cast<unsigned*>(Ah + r * 128 + chunk * 16 + (hl & 3) * 4) = pv;
    }
    __syncthreads();
    // GEMM1: [32x64] @ [64x128]
    {
      f32x4 acc0 = {0.f, 0.f, 0.f, 0.f}, acc1 = acc0, acc2 = acc0, acc3 = acc0;
      const char* abase = Ah + arow * 128;
      const bf16x8* bv = reinterpret_cast<const bf16x8*>(B1p);
      for (int kk = 0; kk < 2; ++kk) {
        bf16x8 a = *reinterpret_cast<const bf16x8*>(abase + (((kk * 4 + (lane >> 4)) ^ axor) * 16));
        const bf16x8* bp = bv + (size_t)kk * 64 + lane;
        acc0 = __builtin_amdgcn_mfma_f32_16x16x32_bf16(a, bp[(size_t)(ctb + 0) * 2 * 64], acc0, 0, 0, 0);
        acc1 = __builtin_amdgcn_mfma_f32_16x16x32_bf16(a, bp[(size_t)(ctb + 1) * 2 * 64], acc1, 0, 0, 0);
        acc2 = __builtin_amdgcn_mfma_f32_16x16x32_bf16(a, bp[(size_t)(ctb + 2) * 2 * 64], acc2, 0, 0, 0);
        acc3 = __builtin_amdgcn_mfma_f32_16x16x32_bf16(a, bp[(size_t)(ctb + 3) * 2 * 64], acc3, 0, 0, 0);
      }
      int prow = rt * 16 + ((lane >> 4) << 2);
      int c0 = ctb * 16 + (lane & 15);
      float bb0 = b1[c0], bb1 = b1[c0 + 16], bb2 = b1[c0 + 32], bb3 = b1[c0 + 48];
      int j2 = (c0 & 7) * 2, cb = c0 >> 3;
#pragma unroll
      for (int q = 0; q < 4; ++q) {
        int rw = prow + q, rx = rw & 7;
        char* hb = Hh + rw * 256;
        *reinterpret_cast<unsigned short*>(hb + (((cb + 0) ^ rx) * 16) + j2) = f2bf(fmaxf(acc0[q] + bb0, 0.f));
        *reinterpret_cast<unsigned short*>(hb + (((cb + 2) ^ rx) * 16) + j2) = f2bf(fmaxf(acc1[q] + bb1, 0.f));
        *reinterpret_cast<unsigned short*>(hb + (((cb + 4) ^ rx) * 16) + j2) = f2bf(fmaxf(acc2[q] + bb2, 0.f));
        *reinterpret_cast<unsigned short*>(hb + (((cb + 6) ^ rx) * 16) + j2) = f2bf(fmaxf(acc3[q] + bb3, 0.f));
      }
    }
    __syncthreads();
    // GEMM2: [32x128] @ [128x64]
    {
      int ct2 = (wave >> 1) * 2;
      f32x4 d0 = {0.f, 0.f, 0.f, 0.f}, d1 = d0;
      const char* hbase = Hh + arow * 256;
      const bf16x8* bv = reinterpret_cast<const bf16x8*>(B2p);
      for (int kk = 0; kk < 4; ++kk) {
        bf16x8 a = *reinterpret_cast<const bf16x8*>(hbase + (((kk * 4 + (lane >> 4)) ^ axor) * 16));
        const bf16x8* bp = bv + (size_t)kk * 64 + lane;
        d0 = __builtin_amdgcn_mfma_f32_16x16x32_bf16(a, bp[(size_t)(ct2 + 0) * 4 * 64], d0, 0, 0, 0);
        d1 = __builtin_amdgcn_mfma_f32_16x16x32_bf16(a, bp[(size_t)(ct2 + 1) * 4 * 64], d1, 0, 0, 0);
      }
      int prow0 = row0 + rt * 16 + ((lane >> 4) << 2);
      int c0 = ct2 * 16 + (lane & 15);
      float bb0 = b2[c0], bb1 = b2[c0 + 16];
#pragma unroll
      for (int q = 0; q < 4; ++q) {
        pel[(size_t)(prow0 + q) * PDM + c0] = f2bf(d0[q] + bb0);
        pel[(size_t)(prow0 + q) * PDM + c0 + 16] = f2bf(d1[q] + bb1);
      }
    }
    __syncthreads();
  }
}

// ---------- peproj (layer 0 only): y0 = concat(x, pel0) @ pe_W + pe_b ----------
__global__ __launch_bounds__(256) void k_peproj_mfma(
    const float* __restrict__ xu, const float* __restrict__ xi,
    const unsigned short* __restrict__ pel,
    const unsigned short* __restrict__ Bp, const float* __restrict__ bias,
    unsigned short* __restrict__ y_bf) {
  __shared__ __align__(16) char Abuf[32 * 384];
  int t = threadIdx.x, wave = t >> 6, lane = t & 63;
  int row0 = blockIdx.x * 32;
  const float* xs = (row0 < NUQ) ? xu : xi;
  int rbase = (row0 < NUQ) ? row0 : row0 - NUQ;
  for (int i = t; i < 32 * 64; i += 256) {
    int r = i >> 6, cp = i & 63;
    float2 v = *reinterpret_cast<const float2*>(&xs[(size_t)(rbase + r) * CC + cp * 2]);
    unsigned pv = (unsigned)f2bf(v.x) | ((unsigned)f2bf(v.y) << 16);
    int chunk = (cp >> 2) ^ (r & 7);
    *reinterpret_cast<unsigned*>(Abuf + r * 384 + chunk * 16 + (cp & 3) * 4) = pv;
  }
  for (int i = t; i < 32 * 32; i += 256) {
    int r = i >> 5, cp = i & 31;
    unsigned pv = *reinterpret_cast<const unsigned*>(&pel[(size_t)(row0 + r) * PDM + cp * 2]);
    int chunk = (16 + (cp >> 2)) ^ (r & 7);
    *reinterpret_cast<unsigned*>(Abuf + r * 384 + chunk * 16 + (cp & 3) * 4) = pv;
  }
  __syncthreads();
  int rt = wave & 1, ctb = (wave >> 1) * 4;
  f32x4 acc0 = {0.f, 0.f, 0.f, 0.f}, acc1 = acc0, acc2 = acc0, acc3 = acc0;
  int arow = rt * 16 + (lane & 15);
  const char* abase = Abuf + arow * 384;
  int axor = arow & 7;
  const bf16x8* bp0 = reinterpret_cast<const bf16x8*>(Bp);
  for (int kk = 0; kk < 6; ++kk) {
    bf16x8 a = *reinterpret_cast<const bf16x8*>(abase + (((kk * 4 + (lane >> 4)) ^ axor) * 16));
    const bf16x8* bp = bp0 + (size_t)kk * 64 + lane;
    acc0 = __builtin_amdgcn_mfma_f32_16x16x32_bf16(a, bp[(size_t)(ctb + 0) * 6 * 64], acc0, 0, 0, 0);
    acc1 = __builtin_amdgcn_mfma_f32_16x16x32_bf16(a, bp[(size_t)(ctb + 1) * 6 * 64], acc1, 0, 0, 0);
    acc2 = __builtin_amdgcn_mfma_f32_16x16x32_bf16(a, bp[(size_t)(ctb + 2) * 6 * 64], acc2, 0, 0, 0);
    acc3 = __builtin_amdgcn_mfma_f32_16x16x32_bf16(a, bp[(size_t)(ctb + 3) * 6 * 64], acc3, 0, 0, 0);
  }
  int prow0 = row0 + rt * 16 + ((lane >> 4) << 2);
  int c0 = ctb * 16 + (lane & 15);
  float b0 = bias[c0], b1 = bias[c0 + 16], b2 = bias[c0 + 32], b3 = bias[c0 + 48];
#pragma unroll
  for (int q = 0; q < 4; ++q) {
    size_t rb = (size_t)(prow0 + q) * CC;
    y_bf[rb + c0]      = f2bf(acc0[q] + b0);
    y_bf[rb + c0 + 16] = f2bf(acc1[q] + b1);
    y_bf[rb + c0 + 32] = f2bf(acc2[q] + b2);
    y_bf[rb + c0 + 48] = f2bf(acc3[q] + b3);
  }
}

// ---------- fused: CSR mean-gather (r5 exact: 2 rows/wave, uint2, unroll-2) + dual GEMM
//            (K=256) + LN + ReLU [+ optional fused next-layer peproj -> y_out] ----------
template <bool FUSE>
__global__ __launch_bounds__(256) void k_sage_mfma(
    const unsigned short* __restrict__ y_bf,
    const int* __restrict__ offU, const int* __restrict__ idxU,
    const int* __restrict__ offI, const int* __restrict__ idxI,
    const unsigned short* __restrict__ BpU, const unsigned short* __restrict__ BpI,
    const float* __restrict__ blU, const float* __restrict__ blI,
    const float* __restrict__ gU, const float* __restrict__ beU,
    const float* __restrict__ gI, const float* __restrict__ beI,
    const unsigned short* __restrict__ pel2, const unsigned short* __restrict__ Bp2,
    const float* __restrict__ bias2,
    unsigned short* __restrict__ y_out, float* __restrict__ xh) {
  __shared__ __align__(16) char U[32 * 132 * 4 + 32 * 8];
  char* Abuf = U;
  float (*preLN)[132] = reinterpret_cast<float (*)[132]>(U);
  float (*stat)[2] = reinterpret_cast<float (*)[2]>(U + 32 * 132 * 4);
  int t = threadIdx.x, wave = t >> 6, lane = t & 63;
  int row0 = blockIdx.x * 32;
  bool isU = row0 < NUQ;
  const int* off = isU ? offU : offI;
  const int* idx = isU ? idxU : idxI;
  int dBase = isU ? 0 : NUQ;
  int sBase = isU ? NUQ : 0;
  const unsigned short* Bp = isU ? BpU : BpI;
  const float* bl = isU ? blU : blI;
  const float* g  = isU ? gU : gI;
  const float* be = isU ? beU : beI;

  // stage: 2 rows per wave (half-waves), 8 B/lane uint2, unroll-2 (r5 measured-best: 117us @2.1TB/s)
  int half = lane >> 5, hl = lane & 31;
  for (int pr = 0; pr < 4; ++pr) {
    int r = wave * 8 + pr * 2 + half;
    int d = row0 + r;
    int e0 = off[d - dBase], e1 = off[d - dBase + 1];
    float s0 = 0.f, s1 = 0.f, s2 = 0.f, s3 = 0.f;
    float t0 = 0.f, t1 = 0.f, t2 = 0.f, t3 = 0.f;
    int e = e0;
    for (; e + 2 <= e1; e += 2) {
      uint2 u = *reinterpret_cast<const uint2*>(&y_bf[(size_t)(sBase + idx[e]) * CC + hl * 4]);
      uint2 v = *reinterpret_cast<const uint2*>(&y_bf[(size_t)(sBase + idx[e + 1]) * CC + hl * 4]);
      s0 += bflo(u.x); s1 += bfhi(u.x); s2 += bflo(u.y); s3 += bfhi(u.y);
      t0 += bflo(v.x); t1 += bfhi(v.x); t2 += bflo(v.y); t3 += bfhi(v.y);
    }
    if (e < e1) {
      uint2 u = *reinterpret_cast<const uint2*>(&y_bf[(size_t)(sBase + idx[e]) * CC + hl * 4]);
      s0 += bflo(u.x); s1 += bfhi(u.x); s2 += bflo(u.y); s3 += bfhi(u.y);
    }
    s0 += t0; s1 += t1; s2 += t2; s3 += t3;
    float inv = 1.0f / fmaxf((float)(e1 - e0), 1.0f);
    int cp0 = hl * 2;
    uint2 pm;
    pm.x = (unsigned)f2bf(s0 * inv) | ((unsigned)f2bf(s1 * inv) << 16);
    pm.y = (unsigned)f2bf(s2 * inv) | ((unsigned)f2bf(s3 * inv) << 16);
    int ch = (cp0 >> 2) ^ (r & 7);
    *reinterpret_cast<uint2*>(Abuf + r * 512 + ch * 16 + (cp0 & 3) * 4) = pm;
    uint2 pv = *reinterpret_cast<const uint2*>(&y_bf[(size_t)(row0 + r) * CC + hl * 4]);
    *reinterpret_cast<uint2*>(Abuf + r * 512 + (16 + ch) * 16 + (cp0 & 3) * 4) = pv;
  }
  __syncthreads();
  // MFMA: K=256 over [mean | y]
  int rt = wave & 1, ctb = (wave >> 1) * 4;
  int arow = rt * 16 + (lane & 15);
  int axor = arow & 7;
  {
    f32x4 acc0 = {0.f, 0.f, 0.f, 0.f}, acc1 = acc0, acc2 = acc0, acc3 = acc0;
    const char* abase = Abuf + arow * 512;
    const bf16x8* bp0 = reinterpret_cast<const bf16x8*>(Bp);
    for (int kk = 0; kk < 8; ++kk) {
      bf16x8 a = *reinterpret_cast<const bf16x8*>(abase + (((kk * 4 + (lane >> 4)) ^ axor) * 16));
      const bf16x8* bp = bp0 + (size_t)kk * 64 + lane;
      acc0 = __builtin_amdgcn_mfma_f32_16x16x32_bf16(a, bp[(size_t)(ctb + 0) * 8 * 64], acc0, 0, 0, 0);
      acc1 = __builtin_amdgcn_mfma_f32_16x16x32_bf16(a, bp[(size_t)(ctb + 1) * 8 * 64], acc1, 0, 0, 0);
      acc2 = __builtin_amdgcn_mfma_f32_16x16x32_bf16(a, bp[(size_t)(ctb + 2) * 8 * 64], acc2, 0, 0, 0);
      acc3 = __builtin_amdgcn_mfma_f32_16x16x32_bf16(a, bp[(size_t)(ctb + 3) * 8 * 64], acc3, 0, 0, 0);
    }
    __syncthreads();   // Abuf dead; preLN aliases it
    int prow = rt * 16 + ((lane >> 4) << 2);
    int c0 = ctb * 16 + (lane & 15);
    float b0 = bl[c0], b1 = bl[c0 + 16], b2 = bl[c0 + 32], b3 = bl[c0 + 48];
#pragma unroll
    for (int q = 0; q < 4; ++q) {
      preLN[prow + q][c0]      = acc0[q] + b0;
      preLN[prow + q][c0 + 16] = acc1[q] + b1;
      preLN[prow + q][c0 + 32] = acc2[q] + b2;
      preLN[prow + q][c0 + 48] = acc3[q] + b3;
    }
  }
  __syncthreads();
  {
    int rr = t >> 3, j = t & 7;
    float s = 0.f, sq = 0.f;
#pragma unroll
    for (int i = 0; i < 16; ++i) { float v = preLN[rr][j + 8 * i]; s += v; sq += v * v; }
    s += __shfl_xor(s, 1); sq += __shfl_xor(sq, 1);
    s += __shfl_xor(s, 2); sq += __shfl_xor(sq, 2);
    s += __shfl_xor(s, 4); sq += __shfl_xor(sq, 4);
    if (j == 0) {
      float mu = s * (1.0f / CC);
      float var = sq * (1.0f / CC) - mu * mu;
      stat[rr][0] = mu;
      stat[rr][1] = rsqrtf(var + 1e-5f);
    }
  }
  __syncthreads();
  if (!FUSE) {
    for (int i = t; i < 32 * CC; i += 256) {
      int r = i >> 7, c = i & 127;
      float v = (preLN[r][c] - stat[r][0]) * stat[r][1] * g[c] + be[c];
      xh[(size_t)(row0 + r) * CC + c] = fmaxf(v, 0.f);
    }
  } else {
    float vx[16];
    int cx = t & 127, rb0 = t >> 7;
    float gc = g[cx], bec = be[cx];
#pragma unroll
    for (int k = 0; k < 16; ++k) {
      int r = rb0 + 2 * k;
      float v = (preLN[r][cx] - stat[r][0]) * stat[r][1] * gc + bec;
      vx[k] = fmaxf(v, 0.f);
    }
    __syncthreads();   // all preLN reads done; Abuf reusable
    {
      int chunkx = cx >> 3;
      int bofs = (cx & 7) * 2;
#pragma unroll
      for (int k = 0; k < 16; ++k) {
        int r = rb0 + 2 * k;
        *reinterpret_cast<unsigned short*>(Abuf + r * 512 + ((chunkx ^ (r & 7)) * 16) + bofs) = f2bf(vx[k]);
      }
    }
    for (int i = t; i < 32 * 32; i += 256) {
      int r = i >> 5, cp = i & 31;
      unsigned pv = *reinterpret_cast<const unsigned*>(&pel2[(size_t)(row0 + r) * PDM + cp * 2]);
      int chunk = 16 + ((cp >> 2) ^ (r & 7));
      *reinterpret_cast<unsigned*>(Abuf + r * 512 + chunk * 16 + (cp & 3) * 4) = pv;
    }
    __syncthreads();
    f32x4 acc0 = {0.f, 0.f, 0.f, 0.f}, acc1 = acc0, acc2 = acc0, acc3 = acc0;
    const char* abase = Abuf + arow * 512;
    const bf16x8* bp0 = reinterpret_cast<const bf16x8*>(Bp2);
    for (int kk = 0; kk < 6; ++kk) {
      bf16x8 a = *reinterpret_cast<const bf16x8*>(abase + (((kk * 4 + (lane >> 4)) ^ axor) * 16));
      const bf16x8* bp = bp0 + (size_t)kk * 64 + lane;
      acc0 = __builtin_amdgcn_mfma_f32_16x16x32_bf16(a, bp[(size_t)(ctb + 0) * 6 * 64], acc0, 0, 0, 0);
      acc1 = __builtin_amdgcn_mfma_f32_16x16x32_bf16(a, bp[(size_t)(ctb + 1) * 6 * 64], acc1, 0, 0, 0);
      acc2 = __builtin_amdgcn_mfma_f32_16x16x32_bf16(a, bp[(size_t)(ctb + 2) * 6 * 64], acc2, 0, 0, 0);
      acc3 = __builtin_amdgcn_mfma_f32_16x16x32_bf16(a, bp[(size_t)(ctb + 3) * 6 * 64], acc3, 0, 0, 0);
    }
    int prow0 = row0 + rt * 16 + ((lane >> 4) << 2);
    int c0 = ctb * 16 + (lane & 15);
    float b0 = bias2[c0], b1 = bias2[c0 + 16], b2 = bias2[c0 + 32], b3 = bias2[c0 + 48];
#pragma unroll
    for (int q = 0; q < 4; ++q) {
      size_t rb = (size_t)(prow0 + q) * CC;
      y_out[rb + c0]      = f2bf(acc0[q] + b0);
      y_out[rb + c0 + 16] = f2bf(acc1[q] + b1);
      y_out[rb + c0 + 32] = f2bf(acc2[q] + b2);
      y_out[rb + c0 + 48] = f2bf(acc3[q] + b3);
    }
  }
}

extern "C" void kernel_launch(void* const* d_in, const int* in_sizes, int n_in,
                              void* d_out, int out_size, void* d_ws, size_t ws_size,
                              hipStream_t stream) {
  const float* x_user = (const float*)d_in[0];
  const float* x_item = (const float*)d_in[1];
  const float* PE     = (const float*)d_in[2];
  const float* sui_Wl = (const float*)d_in[3];
  const float* sui_bl = (const float*)d_in[4];
  const float* sui_Wr = (const float*)d_in[5];
  const float* siu_Wl = (const float*)d_in[6];
  const float* siu_bl = (const float*)d_in[7];
  const float* siu_Wr = (const float*)d_in[8];
  const float* lnu_g  = (const float*)d_in[9];
  const float* lnu_b  = (const float*)d_in[10];
  const float* lni_g  = (const float*)d_in[11];
  const float* lni_b  = (const float*)d_in[12];
  const float* phi_eps = (const float*)d_in[13];
  const float* phi_W1  = (const float*)d_in[14];
  const float* phi_b1  = (const float*)d_in[15];
  const float* phi_W2  = (const float*)d_in[16];
  const float* phi_b2  = (const float*)d_in[17];
  const float* pe_W    = (const float*)d_in[18];
  const float* pe_b    = (const float*)d_in[19];
  const int* edge_ui   = (const int*)d_in[20];
  const int* edge_iu   = (const int*)d_in[21];
  const int* edge_hom  = (const int*)d_in[22];

  float* xh = (float*)d_out;                                    // [NH][C] f32 (final)
  unsigned short* y0    = (unsigned short*)d_ws;                // [NH][C]
  unsigned short* y1    = y0 + (size_t)NHN * CC;                // [NH][C]
  unsigned short* pel0  = y1 + (size_t)NHN * CC;                // [NH][PD]
  unsigned short* pel1  = pel0 + (size_t)NHN * PDM;             // [NH][PD]
  unsigned short* pe_bf = pel1 + (size_t)NHN * PDM;             // [NH][PD]
  int* ip = (int*)(pe_bf + (size_t)NHN * PDM);
  int* cnt      = ip;             ip += NHN;
  int* cnt_hom  = ip;             ip += NHN;
  int* cur_u    = ip;             ip += NUQ;
  int* cur_i    = ip;             ip += NIQ;
  int* cur_h    = ip;             ip += NHN;
  int* off_iu   = ip;             ip += NUQ + 1;
  int* off_ui   = ip;             ip += NIQ + 1;
  int* off_hom  = ip;             ip += NHN + 1;
  int* idx_ui   = ip;             ip += EHET;
  int* idx_iu   = ip;             ip += EHET;
  int* idx_hom  = ip;             ip += EHOM;
  int* blksum   = ip;             ip += 3 * 256;
  int* blkoff   = ip;             ip += 3 * 257;
  unsigned short* packs = (unsigned short*)((((size_t)(ip)) + 15) & ~(size_t)15);
  unsigned short* sageP = packs;                    // [L][2 types] x 32768
  unsigned short* peP   = sageP + 4 * 32768;        // [L] x 24576
  unsigned short* g1P   = peP + 2 * 24576;          // [L] x 8192
  unsigned short* g2P   = g1P + 2 * 8192;           // [L] x 8192

  (void)hipMemsetAsync(cnt, 0, (size_t)(2 * NHN + NUQ + NIQ + NHN) * sizeof(int), stream);

  // fused: histogram (2M atomics) + PE->bf16 stream (6.4M elems)
  k_setup2<<<(2 * EHET + EHOM + NHN * PDM / 2 + 255) / 256, 256, 0, stream>>>(
      edge_ui + EHET, edge_iu + EHET, edge_hom + EHOM, PE, (unsigned*)pe_bf, cnt, cnt_hom);

  k_scan1f<<<NB0 + NB1 + NB2, 256, 0, stream>>>(cnt, cnt_hom, off_iu, off_ui, off_hom, blksum);
  k_scan2f<<<3, 256, 0, stream>>>(blksum, blkoff);
  k_scan3f<<<2 * G0 + G2, 256, 0, stream>>>(off_iu, off_ui, off_hom, blkoff);

  // fused: CSR fill (3 graphs) + weight prepack (14 segments)
  k_fillpack<<<FILLB + 14 * 96, 256, 0, stream>>>(
      edge_ui, edge_iu, edge_hom, off_ui, off_iu, off_hom,
      cur_i, cur_u, cur_h, idx_ui, idx_iu, idx_hom,
      siu_Wl, siu_Wr, sui_Wl, sui_Wr, pe_W, phi_W1, phi_W2,
      sageP, peP, g1P, g2P);

  k_gin2<<<NHN / 32, 256, 0, stream>>>(PE, off_hom, idx_hom, pe_bf,
                                       g1P, phi_b1, g2P, phi_b2, phi_eps, pel0, pel1);
  k_peproj_mfma<<<NHN / 32, 256, 0, stream>>>(x_user, x_item, pel0, peP, pe_b, y0);

  // layer 0: SAGE + LN + ReLU + fused layer-1 peproj -> y1 (no xh round-trip)
  k_sage_mfma<true><<<NHN / 32, 256, 0, stream>>>(y0,
      off_iu, idx_iu, off_ui, idx_ui,
      sageP + (size_t)0 * 32768, sageP + (size_t)1 * 32768,
      siu_bl, sui_bl, lnu_g, lnu_b, lni_g, lni_b,
      pel1, peP + 24576, pe_b + CC, y1, nullptr);

  // layer 1: SAGE + LN + ReLU -> xh (final f32 output)
  k_sage_mfma<false><<<NHN / 32, 256, 0, stream>>>(y1,
      off_iu, idx_iu, off_ui, idx_ui,
      sageP + (size_t)2 * 32768, sageP + (size_t)3 * 32768,
      siu_bl + CC, sui_bl + CC,
      lnu_g + CC, lnu_b + CC, lni_g + CC, lni_b + CC,
      nullptr, nullptr, nullptr, nullptr, xh);
}

// Round 13
// 556.068 us; speedup vs baseline: 1.1426x; 1.1426x over previous
//
#include <hip/hip_runtime.h>

#define NUQ 100000
#define NIQ 100000
#define NHN 200000
#define CC 128
#define PDM 64
#define PHM 128
#define EHET 500000
#define EHOM 1000000
#define SCAN_CHUNK 2048

typedef __attribute__((ext_vector_type(8))) short bf16x8;
typedef __attribute__((ext_vector_type(4))) float f32x4;

__device__ inline unsigned short f2bf(float x) {
  union { float f; unsigned u; } c; c.f = x;
  unsigned r = c.u + 0x7FFF + ((c.u >> 16) & 1);
  return (unsigned short)(r >> 16);
}
__device__ inline float bflo(unsigned u) { union { unsigned u; float f; } c; c.u = u << 16; return c.f; }
__device__ inline float bfhi(unsigned u) { union { unsigned u; float f; } c; c.u = u & 0xffff0000u; return c.f; }

// ---------- fused: degree counts (het both dirs + hom) + PE->bf16 convert ----------
__global__ void k_setup2(const int* __restrict__ eui_dst, const int* __restrict__ eiu_dst,
                         const int* __restrict__ ehom_dst,
                         const float* __restrict__ pe, unsigned* __restrict__ pe_bf_out,
                         int* __restrict__ cnt, int* __restrict__ cnt_hom) {
  int i = blockIdx.x * 256 + threadIdx.x;
  const int EA = 2 * EHET + EHOM;
  if (i < EHET) {
    atomicAdd(&cnt[NUQ + eui_dst[i]], 1);
  } else if (i < 2 * EHET) {
    atomicAdd(&cnt[eiu_dst[i - EHET]], 1);
  } else if (i < EA) {
    atomicAdd(&cnt_hom[ehom_dst[i - 2 * EHET]], 1);
  } else if (i < EA + NHN * PDM / 2) {
    int j = i - EA;
    float2 v = *reinterpret_cast<const float2*>(&pe[(size_t)j * 2]);
    pe_bf_out[j] = (unsigned)f2bf(v.x) | ((unsigned)f2bf(v.y) << 16);
  }
}

// ---------- fused 3-segment exclusive scan ----------
#define NB0 49
#define NB1 49
#define NB2 98
__global__ __launch_bounds__(256) void k_scan1f(const int* __restrict__ cnt, const int* __restrict__ cnt_hom,
                                                int* __restrict__ off_iu, int* __restrict__ off_ui,
                                                int* __restrict__ off_hom, int* __restrict__ blksum) {
  const int* in; int n; int* out; int* bs; int b;
  int blk = blockIdx.x;
  if (blk < NB0)            { in = cnt;       n = NUQ; out = off_iu;  bs = blksum;       b = blk; }
  else if (blk < NB0 + NB1) { in = cnt + NUQ; n = NIQ; out = off_ui;  bs = blksum + 256; b = blk - NB0; }
  else                      { in = cnt_hom;   n = NHN; out = off_hom; bs = blksum + 512; b = blk - NB0 - NB1; }
  __shared__ int sh[256];
  int t = threadIdx.x;
  int base = b * SCAN_CHUNK + t * 8;
  int v[8]; int s = 0;
#pragma unroll
  for (int i = 0; i < 8; ++i) {
    int x = (base + i < n) ? in[base + i] : 0;
    v[i] = s;
    s += x;
  }
  sh[t] = s; __syncthreads();
  for (int d = 1; d < 256; d <<= 1) {
    int x = (t >= d) ? sh[t - d] : 0;
    __syncthreads();
    sh[t] += x;
    __syncthreads();
  }
  int texcl = sh[t] - s;
#pragma unroll
  for (int i = 0; i < 8; ++i)
    if (base + i < n) out[base + i] = texcl + v[i];
  if (t == 255) bs[b] = sh[255];
}

__global__ void k_scan2f(const int* __restrict__ blksum, int* __restrict__ blkoff) {
  int seg = blockIdx.x;
  int nb = (seg == 2) ? NB2 : NB0;
  const int* bs = blksum + seg * 256;
  int* bo = blkoff + seg * 257;
  __shared__ int sh[256];
  int t = threadIdx.x;
  int x0 = (t < nb) ? bs[t] : 0;
  sh[t] = x0; __syncthreads();
  for (int d = 1; d < 256; d <<= 1) {
    int x = (t >= d) ? sh[t - d] : 0;
    __syncthreads();
    sh[t] += x;
    __syncthreads();
  }
  if (t < nb) bo[t] = sh[t] - x0;
  if (t == 0) bo[nb] = sh[255];
}

#define G0 392
#define G2 784
__global__ void k_scan3f(int* __restrict__ off_iu, int* __restrict__ off_ui, int* __restrict__ off_hom,
                         const int* __restrict__ blkoff) {
  int blk = blockIdx.x;
  int* off; int n; const int* bo; int nb; int b;
  if (blk < G0)           { off = off_iu;  n = NUQ; bo = blkoff;       nb = NB0; b = blk; }
  else if (blk < 2 * G0)  { off = off_ui;  n = NIQ; bo = blkoff + 257; nb = NB1; b = blk - G0; }
  else                    { off = off_hom; n = NHN; bo = blkoff + 514; nb = NB2; b = blk - 2 * G0; }
  int i = b * 256 + threadIdx.x;
  if (i < n) off[i] += bo[i >> 11];
  else if (i == n) off[n] = bo[nb];
}

// ---------- single fused weight-prepack helper ----------
__device__ inline void pack_one(const float* W, int i, int NC, int kkBase, int KKtot,
                                unsigned short* out) {
  int k = i / NC, n = i % NC;
  int kk = kkBase + (k >> 5);
  int lane = (n & 15) + (((k >> 3) & 3) << 4);
  int j8 = k & 7;
  int o16 = ((n >> 4) * KKtot + kk) * 64 + lane;
  out[o16 * 8 + j8] = f2bf(W[i]);
}

// ---------- fused: CSR fill (atomic cursor) + weight prepack ----------
#define FILLB 7813   // ceil(2*EHET+EHOM / 256)
__global__ __launch_bounds__(256) void k_fillpack(
    const int* __restrict__ edge_ui, const int* __restrict__ edge_iu,
    const int* __restrict__ edge_hom,
    const int* __restrict__ off_ui, const int* __restrict__ off_iu,
    const int* __restrict__ off_hom,
    int* __restrict__ cur_i, int* __restrict__ cur_u, int* __restrict__ cur_h,
    int* __restrict__ idx_ui, int* __restrict__ idx_iu, int* __restrict__ idx_hom,
    const float* __restrict__ siu_Wl, const float* __restrict__ siu_Wr,
    const float* __restrict__ sui_Wl, const float* __restrict__ sui_Wr,
    const float* __restrict__ pe_W, const float* __restrict__ phi_W1, const float* __restrict__ phi_W2,
    unsigned short* __restrict__ sageP, unsigned short* __restrict__ peP,
    unsigned short* __restrict__ g1P, unsigned short* __restrict__ g2P) {
  int blk = blockIdx.x;
  if (blk < FILLB) {
    int gid = blk * 256 + threadIdx.x;
    if (gid < EHET) {
      int d = edge_ui[EHET + gid];
      int p = atomicAdd(&cur_i[d], 1);
      idx_ui[off_ui[d] + p] = edge_ui[gid];
    } else if (gid < 2 * EHET) {
      int e = gid - EHET;
      int d = edge_iu[EHET + e];
      int p = atomicAdd(&cur_u[d], 1);
      idx_iu[off_iu[d] + p] = edge_iu[e];
    } else if (gid < 2 * EHET + EHOM) {
      int e = gid - 2 * EHET;
      int d = edge_hom[EHOM + e];
      int p = atomicAdd(&cur_h[d], 1);
      idx_hom[off_hom[d] + p] = edge_hom[e];
    }
    return;
  }
  int pb = blk - FILLB;
  int seg = pb / 96;
  int i = (pb % 96) * 256 + threadIdx.x;
  int l = seg / 7, j = seg % 7;
  switch (j) {
    case 0: if (i < CC * 128) pack_one(siu_Wl + (size_t)l * CC * CC, i, 128, 0, 8, sageP + (size_t)(l * 2) * 32768); break;
    case 1: if (i < CC * 128) pack_one(siu_Wr + (size_t)l * CC * CC, i, 128, 4, 8, sageP + (size_t)(l * 2) * 32768); break;
    case 2: if (i < CC * 128) pack_one(sui_Wl + (size_t)l * CC * CC, i, 128, 0, 8, sageP + (size_t)(l * 2 + 1) * 32768); break;
    case 3: if (i < CC * 128) pack_one(sui_Wr + (size_t)l * CC * CC, i, 128, 4, 8, sageP + (size_t)(l * 2 + 1) * 32768); break;
    case 4: if (i < (CC + PDM) * 128) pack_one(pe_W + (size_t)l * (CC + PDM) * CC, i, 128, 0, 6, peP + (size_t)l * 24576); break;
    case 5: if (i < PDM * 128) pack_one(phi_W1 + (size_t)l * PDM * PHM, i, 128, 0, 2, g1P + (size_t)l * 8192); break;
    case 6: if (i < PHM * 64) pack_one(phi_W2 + (size_t)l * PHM * PDM, i, 64, 0, 4, g2P + (size_t)l * 8192); break;
  }
}

// ---------- fused GIN: CSR gather (clamped unroll-8) + MLP MFMA, BOTH layers ----------
__global__ __launch_bounds__(256) void k_gin2(
    const float* __restrict__ pe,
    const int* __restrict__ off, const int* __restrict__ idx,
    const unsigned short* __restrict__ pe_bf,
    const unsigned short* __restrict__ g1P, const float* __restrict__ phi_b1,
    const unsigned short* __restrict__ g2P, const float* __restrict__ phi_b2,
    const float* __restrict__ eps_p,
    unsigned short* __restrict__ pel0, unsigned short* __restrict__ pel1) {
  __shared__ __align__(16) char Ah[32 * 128];
  __shared__ __align__(16) char Hh[32 * 256];
  int t = threadIdx.x, wave = t >> 6, lane = t & 63;
  int row0 = blockIdx.x * 32;
  int half = lane >> 5, hl = lane & 31;
  int rt = wave & 1, ctb = (wave >> 1) * 4;
  int arow = rt * 16 + (lane & 15);
  int axor = arow & 7;
  float sg0[4], sg1[4], ps0[4], ps1[4];
#pragma unroll
  for (int pr = 0; pr < 4; ++pr) {
    int r = wave * 8 + pr * 2 + half;
    int n = row0 + r;
    int e0 = off[n], e1 = off[n + 1], eL = e1 - 1;
    float s0 = 0.f, s1 = 0.f;
    for (int e = e0; e < e1; e += 8) {
      int q1 = (e + 1 < e1) ? e + 1 : eL, q2 = (e + 2 < e1) ? e + 2 : eL;
      int q3 = (e + 3 < e1) ? e + 3 : eL, q4 = (e + 4 < e1) ? e + 4 : eL;
      int q5 = (e + 5 < e1) ? e + 5 : eL, q6 = (e + 6 < e1) ? e + 6 : eL;
      int q7 = (e + 7 < e1) ? e + 7 : eL;
      int i0 = idx[e], i1 = idx[q1], i2 = idx[q2], i3 = idx[q3];
      int i4 = idx[q4], i5 = idx[q5], i6 = idx[q6], i7 = idx[q7];
      unsigned u0 = *reinterpret_cast<const unsigned*>(&pe_bf[(size_t)i0 * PDM + hl * 2]);
      unsigned u1 = *reinterpret_cast<const unsigned*>(&pe_bf[(size_t)i1 * PDM + hl * 2]);
      unsigned u2 = *reinterpret_cast<const unsigned*>(&pe_bf[(size_t)i2 * PDM + hl * 2]);
      unsigned u3 = *reinterpret_cast<const unsigned*>(&pe_bf[(size_t)i3 * PDM + hl * 2]);
      unsigned u4 = *reinterpret_cast<const unsigned*>(&pe_bf[(size_t)i4 * PDM + hl * 2]);
      unsigned u5 = *reinterpret_cast<const unsigned*>(&pe_bf[(size_t)i5 * PDM + hl * 2]);
      unsigned u6 = *reinterpret_cast<const unsigned*>(&pe_bf[(size_t)i6 * PDM + hl * 2]);
      unsigned u7 = *reinterpret_cast<const unsigned*>(&pe_bf[(size_t)i7 * PDM + hl * 2]);
      unsigned m1 = (e + 1 < e1) ? ~0u : 0u, m2 = (e + 2 < e1) ? ~0u : 0u;
      unsigned m3 = (e + 3 < e1) ? ~0u : 0u, m4 = (e + 4 < e1) ? ~0u : 0u;
      unsigned m5 = (e + 5 < e1) ? ~0u : 0u, m6 = (e + 6 < e1) ? ~0u : 0u;
      unsigned m7 = (e + 7 < e1) ? ~0u : 0u;
      u1 &= m1; u2 &= m2; u3 &= m3; u4 &= m4; u5 &= m5; u6 &= m6; u7 &= m7;
      s0 += ((bflo(u0) + bflo(u1)) + (bflo(u2) + bflo(u3))) +
            ((bflo(u4) + bflo(u5)) + (bflo(u6) + bflo(u7)));
      s1 += ((bfhi(u0) + bfhi(u1)) + (bfhi(u2) + bfhi(u3))) +
            ((bfhi(u4) + bfhi(u5)) + (bfhi(u6) + bfhi(u7)));
    }
    sg0[pr] = s0; sg1[pr] = s1;
    float2 p2 = *reinterpret_cast<const float2*>(&pe[(size_t)n * PDM + hl * 2]);
    ps0[pr] = p2.x; ps1[pr] = p2.y;
  }
#pragma unroll
  for (int l = 0; l < 2; ++l) {
    const unsigned short* B1p = g1P + (size_t)l * 8192;
    const unsigned short* B2p = g2P + (size_t)l * 8192;
    const float* b1 = phi_b1 + (size_t)l * PHM;
    const float* b2 = phi_b2 + (size_t)l * PDM;
    unsigned short* pel = l ? pel1 : pel0;
    float e1v = 1.0f + eps_p[l];
#pragma unroll
    for (int pr = 0; pr < 4; ++pr) {
      int r = wave * 8 + pr * 2 + half;
      unsigned pv = (unsigned)f2bf(e1v * ps0[pr] + sg0[pr]) |
                    ((unsigned)f2bf(e1v * ps1[pr] + sg1[pr]) << 16);
      int chunk = (hl >> 2) ^ (r & 7);
      *reinterpret_cast<unsigned*>(Ah + r * 128 + chunk * 16 + (hl & 3) * 4) = pv;
    }
    __syncthreads();
    // GEMM1: [32x64] @ [64x128]
    {
      f32x4 acc0 = {0.f, 0.f, 0.f, 0.f}, acc1 = acc0, acc2 = acc0, acc3 = acc0;
      const char* abase = Ah + arow * 128;
      const bf16x8* bv = reinterpret_cast<const bf16x8*>(B1p);
      for (int kk = 0; kk < 2; ++kk) {
        bf16x8 a = *reinterpret_cast<const bf16x8*>(abase + (((kk * 4 + (lane >> 4)) ^ axor) * 16));
        const bf16x8* bp = bv + (size_t)kk * 64 + lane;
        acc0 = __builtin_amdgcn_mfma_f32_16x16x32_bf16(a, bp[(size_t)(ctb + 0) * 2 * 64], acc0, 0, 0, 0);
        acc1 = __builtin_amdgcn_mfma_f32_16x16x32_bf16(a, bp[(size_t)(ctb + 1) * 2 * 64], acc1, 0, 0, 0);
        acc2 = __builtin_amdgcn_mfma_f32_16x16x32_bf16(a, bp[(size_t)(ctb + 2) * 2 * 64], acc2, 0, 0, 0);
        acc3 = __builtin_amdgcn_mfma_f32_16x16x32_bf16(a, bp[(size_t)(ctb + 3) * 2 * 64], acc3, 0, 0, 0);
      }
      int prow = rt * 16 + ((lane >> 4) << 2);
      int c0 = ctb * 16 + (lane & 15);
      float bb0 = b1[c0], bb1 = b1[c0 + 16], bb2 = b1[c0 + 32], bb3 = b1[c0 + 48];
      int j2 = (c0 & 7) * 2, cb = c0 >> 3;
#pragma unroll
      for (int q = 0; q < 4; ++q) {
        int rw = prow + q, rx = rw & 7;
        char* hb = Hh + rw * 256;
        *reinterpret_cast<unsigned short*>(hb + (((cb + 0) ^ rx) * 16) + j2) = f2bf(fmaxf(acc0[q] + bb0, 0.f));
        *reinterpret_cast<unsigned short*>(hb + (((cb + 2) ^ rx) * 16) + j2) = f2bf(fmaxf(acc1[q] + bb1, 0.f));
        *reinterpret_cast<unsigned short*>(hb + (((cb + 4) ^ rx) * 16) + j2) = f2bf(fmaxf(acc2[q] + bb2, 0.f));
        *reinterpret_cast<unsigned short*>(hb + (((cb + 6) ^ rx) * 16) + j2) = f2bf(fmaxf(acc3[q] + bb3, 0.f));
      }
    }
    __syncthreads();
    // GEMM2: [32x128] @ [128x64]
    {
      int ct2 = (wave >> 1) * 2;
      f32x4 d0 = {0.f, 0.f, 0.f, 0.f}, d1 = d0;
      const char* hbase = Hh + arow * 256;
      const bf16x8* bv = reinterpret_cast<const bf16x8*>(B2p);
      for (int kk = 0; kk < 4; ++kk) {
        bf16x8 a = *reinterpret_cast<const bf16x8*>(hbase + (((kk * 4 + (lane >> 4)) ^ axor) * 16));
        const bf16x8* bp = bv + (size_t)kk * 64 + lane;
        d0 = __builtin_amdgcn_mfma_f32_16x16x32_bf16(a, bp[(size_t)(ct2 + 0) * 4 * 64], d0, 0, 0, 0);
        d1 = __builtin_amdgcn_mfma_f32_16x16x32_bf16(a, bp[(size_t)(ct2 + 1) * 4 * 64], d1, 0, 0, 0);
      }
      int prow0 = row0 + rt * 16 + ((lane >> 4) << 2);
      int c0 = ct2 * 16 + (lane & 15);
      float bb0 = b2[c0], bb1 = b2[c0 + 16];
#pragma unroll
      for (int q = 0; q < 4; ++q) {
        pel[(size_t)(prow0 + q) * PDM + c0] = f2bf(d0[q] + bb0);
        pel[(size_t)(prow0 + q) * PDM + c0 + 16] = f2bf(d1[q] + bb1);
      }
    }
    __syncthreads();
  }
}

// ---------- peproj (layer 0 only): y0 = concat(x, pel0) @ pe_W + pe_b ----------
__global__ __launch_bounds__(256) void k_peproj_mfma(
    const float* __restrict__ xu, const float* __restrict__ xi,
    const unsigned short* __restrict__ pel,
    const unsigned short* __restrict__ Bp, const float* __restrict__ bias,
    unsigned short* __restrict__ y_bf) {
  __shared__ __align__(16) char Abuf[32 * 384];
  int t = threadIdx.x, wave = t >> 6, lane = t & 63;
  int row0 = blockIdx.x * 32;
  const float* xs = (row0 < NUQ) ? xu : xi;
  int rbase = (row0 < NUQ) ? row0 : row0 - NUQ;
  for (int i = t; i < 32 * 64; i += 256) {
    int r = i >> 6, cp = i & 63;
    float2 v = *reinterpret_cast<const float2*>(&xs[(size_t)(rbase + r) * CC + cp * 2]);
    unsigned pv = (unsigned)f2bf(v.x) | ((unsigned)f2bf(v.y) << 16);
    int chunk = (cp >> 2) ^ (r & 7);
    *reinterpret_cast<unsigned*>(Abuf + r * 384 + chunk * 16 + (cp & 3) * 4) = pv;
  }
  for (int i = t; i < 32 * 32; i += 256) {
    int r = i >> 5, cp = i & 31;
    unsigned pv = *reinterpret_cast<const unsigned*>(&pel[(size_t)(row0 + r) * PDM + cp * 2]);
    int chunk = (16 + (cp >> 2)) ^ (r & 7);
    *reinterpret_cast<unsigned*>(Abuf + r * 384 + chunk * 16 + (cp & 3) * 4) = pv;
  }
  __syncthreads();
  int rt = wave & 1, ctb = (wave >> 1) * 4;
  f32x4 acc0 = {0.f, 0.f, 0.f, 0.f}, acc1 = acc0, acc2 = acc0, acc3 = acc0;
  int arow = rt * 16 + (lane & 15);
  const char* abase = Abuf + arow * 384;
  int axor = arow & 7;
  const bf16x8* bp0 = reinterpret_cast<const bf16x8*>(Bp);
  for (int kk = 0; kk < 6; ++kk) {
    bf16x8 a = *reinterpret_cast<const bf16x8*>(abase + (((kk * 4 + (lane >> 4)) ^ axor) * 16));
    const bf16x8* bp = bp0 + (size_t)kk * 64 + lane;
    acc0 = __builtin_amdgcn_mfma_f32_16x16x32_bf16(a, bp[(size_t)(ctb + 0) * 6 * 64], acc0, 0, 0, 0);
    acc1 = __builtin_amdgcn_mfma_f32_16x16x32_bf16(a, bp[(size_t)(ctb + 1) * 6 * 64], acc1, 0, 0, 0);
    acc2 = __builtin_amdgcn_mfma_f32_16x16x32_bf16(a, bp[(size_t)(ctb + 2) * 6 * 64], acc2, 0, 0, 0);
    acc3 = __builtin_amdgcn_mfma_f32_16x16x32_bf16(a, bp[(size_t)(ctb + 3) * 6 * 64], acc3, 0, 0, 0);
  }
  int prow0 = row0 + rt * 16 + ((lane >> 4) << 2);
  int c0 = ctb * 16 + (lane & 15);
  float b0 = bias[c0], b1 = bias[c0 + 16], b2 = bias[c0 + 32], b3 = bias[c0 + 48];
#pragma unroll
  for (int q = 0; q < 4; ++q) {
    size_t rb = (size_t)(prow0 + q) * CC;
    y_bf[rb + c0]      = f2bf(acc0[q] + b0);
    y_bf[rb + c0 + 16] = f2bf(acc1[q] + b1);
    y_bf[rb + c0 + 32] = f2bf(acc2[q] + b2);
    y_bf[rb + c0 + 48] = f2bf(acc3[q] + b3);
  }
}

// ---------- fused: CSR mean-gather (2 rows/wave, clamped unroll-8) + dual GEMM (K=256)
//            + LN + ReLU [+ optional fused next-layer peproj -> y_out] ----------
template <bool FUSE>
__global__ __launch_bounds__(256) void k_sage_mfma(
    const unsigned short* __restrict__ y_bf,
    const int* __restrict__ offU, const int* __restrict__ idxU,
    const int* __restrict__ offI, const int* __restrict__ idxI,
    const int* __restrict__ cnt,
    const unsigned short* __restrict__ BpU, const unsigned short* __restrict__ BpI,
    const float* __restrict__ blU, const float* __restrict__ blI,
    const float* __restrict__ gU, const float* __restrict__ beU,
    const float* __restrict__ gI, const float* __restrict__ beI,
    const unsigned short* __restrict__ pel2, const unsigned short* __restrict__ Bp2,
    const float* __restrict__ bias2,
    unsigned short* __restrict__ y_out, float* __restrict__ xh) {
  __shared__ __align__(16) char U[32 * 132 * 4 + 32 * 8];
  char* Abuf = U;
  float (*preLN)[132] = reinterpret_cast<float (*)[132]>(U);
  float (*stat)[2] = reinterpret_cast<float (*)[2]>(U + 32 * 132 * 4);
  int t = threadIdx.x, wave = t >> 6, lane = t & 63;
  int row0 = blockIdx.x * 32;
  bool isU = row0 < NUQ;
  const int* off = isU ? offU : offI;
  const int* idx = isU ? idxU : idxI;
  int dBase = isU ? 0 : NUQ;
  int sBase = isU ? NUQ : 0;
  const unsigned short* Bp = isU ? BpU : BpI;
  const float* bl = isU ? blU : blI;
  const float* g  = isU ? gU : gI;
  const float* be = isU ? beU : beI;

  // stage: 2 rows per wave (half-waves), 8 B/lane uint2, clamped branch-free unroll-8
  int half = lane >> 5, hl = lane & 31;
  for (int pr = 0; pr < 4; ++pr) {
    int r = wave * 8 + pr * 2 + half;
    int d = row0 + r;
    int e0 = off[d - dBase], e1 = off[d - dBase + 1], eL = e1 - 1;
    float s0 = 0.f, s1 = 0.f, s2 = 0.f, s3 = 0.f;
    for (int e = e0; e < e1; e += 8) {
      int q1 = (e + 1 < e1) ? e + 1 : eL, q2 = (e + 2 < e1) ? e + 2 : eL;
      int q3 = (e + 3 < e1) ? e + 3 : eL, q4 = (e + 4 < e1) ? e + 4 : eL;
      int q5 = (e + 5 < e1) ? e + 5 : eL, q6 = (e + 6 < e1) ? e + 6 : eL;
      int q7 = (e + 7 < e1) ? e + 7 : eL;
      int i0 = idx[e], i1 = idx[q1], i2 = idx[q2], i3 = idx[q3];
      int i4 = idx[q4], i5 = idx[q5], i6 = idx[q6], i7 = idx[q7];
      uint2 u0 = *reinterpret_cast<const uint2*>(&y_bf[(size_t)(sBase + i0) * CC + hl * 4]);
      uint2 u1 = *reinterpret_cast<const uint2*>(&y_bf[(size_t)(sBase + i1) * CC + hl * 4]);
      uint2 u2 = *reinterpret_cast<const uint2*>(&y_bf[(size_t)(sBase + i2) * CC + hl * 4]);
      uint2 u3 = *reinterpret_cast<const uint2*>(&y_bf[(size_t)(sBase + i3) * CC + hl * 4]);
      uint2 u4 = *reinterpret_cast<const uint2*>(&y_bf[(size_t)(sBase + i4) * CC + hl * 4]);
      uint2 u5 = *reinterpret_cast<const uint2*>(&y_bf[(size_t)(sBase + i5) * CC + hl * 4]);
      uint2 u6 = *reinterpret_cast<const uint2*>(&y_bf[(size_t)(sBase + i6) * CC + hl * 4]);
      uint2 u7 = *reinterpret_cast<const uint2*>(&y_bf[(size_t)(sBase + i7) * CC + hl * 4]);
      unsigned m1 = (e + 1 < e1) ? ~0u : 0u, m2 = (e + 2 < e1) ? ~0u : 0u;
      unsigned m3 = (e + 3 < e1) ? ~0u : 0u, m4 = (e + 4 < e1) ? ~0u : 0u;
      unsigned m5 = (e + 5 < e1) ? ~0u : 0u, m6 = (e + 6 < e1) ? ~0u : 0u;
      unsigned m7 = (e + 7 < e1) ? ~0u : 0u;
      u1.x &= m1; u1.y &= m1; u2.x &= m2; u2.y &= m2;
      u3.x &= m3; u3.y &= m3; u4.x &= m4; u4.y &= m4;
      u5.x &= m5; u5.y &= m5; u6.x &= m6; u6.y &= m6;
      u7.x &= m7; u7.y &= m7;
      s0 += ((bflo(u0.x) + bflo(u1.x)) + (bflo(u2.x) + bflo(u3.x))) +
            ((bflo(u4.x) + bflo(u5.x)) + (bflo(u6.x) + bflo(u7.x)));
      s1 += ((bfhi(u0.x) + bfhi(u1.x)) + (bfhi(u2.x) + bfhi(u3.x))) +
            ((bfhi(u4.x) + bfhi(u5.x)) + (bfhi(u6.x) + bfhi(u7.x)));
      s2 += ((bflo(u0.y) + bflo(u1.y)) + (bflo(u2.y) + bflo(u3.y))) +
            ((bflo(u4.y) + bflo(u5.y)) + (bflo(u6.y) + bflo(u7.y)));
      s3 += ((bfhi(u0.y) + bfhi(u1.y)) + (bfhi(u2.y) + bfhi(u3.y))) +
            ((bfhi(u4.y) + bfhi(u5.y)) + (bfhi(u6.y) + bfhi(u7.y)));
    }
    float inv = 1.0f / fmaxf((float)cnt[d], 1.0f);
    int cp0 = hl * 2;
    uint2 pm;
    pm.x = (unsigned)f2bf(s0 * inv) | ((unsigned)f2bf(s1 * inv) << 16);
    pm.y = (unsigned)f2bf(s2 * inv) | ((unsigned)f2bf(s3 * inv) << 16);
    int ch = (cp0 >> 2) ^ (r & 7);
    *reinterpret_cast<uint2*>(Abuf + r * 512 + ch * 16 + (cp0 & 3) * 4) = pm;
    uint2 pv = *reinterpret_cast<const uint2*>(&y_bf[(size_t)(row0 + r) * CC + hl * 4]);
    *reinterpret_cast<uint2*>(Abuf + r * 512 + (16 + ch) * 16 + (cp0 & 3) * 4) = pv;
  }
  __syncthreads();
  // MFMA: K=256 over [mean | y]
  int rt = wave & 1, ctb = (wave >> 1) * 4;
  int arow = rt * 16 + (lane & 15);
  int axor = arow & 7;
  {
    f32x4 acc0 = {0.f, 0.f, 0.f, 0.f}, acc1 = acc0, acc2 = acc0, acc3 = acc0;
    const char* abase = Abuf + arow * 512;
    const bf16x8* bp0 = reinterpret_cast<const bf16x8*>(Bp);
    for (int kk = 0; kk < 8; ++kk) {
      bf16x8 a = *reinterpret_cast<const bf16x8*>(abase + (((kk * 4 + (lane >> 4)) ^ axor) * 16));
      const bf16x8* bp = bp0 + (size_t)kk * 64 + lane;
      acc0 = __builtin_amdgcn_mfma_f32_16x16x32_bf16(a, bp[(size_t)(ctb + 0) * 8 * 64], acc0, 0, 0, 0);
      acc1 = __builtin_amdgcn_mfma_f32_16x16x32_bf16(a, bp[(size_t)(ctb + 1) * 8 * 64], acc1, 0, 0, 0);
      acc2 = __builtin_amdgcn_mfma_f32_16x16x32_bf16(a, bp[(size_t)(ctb + 2) * 8 * 64], acc2, 0, 0, 0);
      acc3 = __builtin_amdgcn_mfma_f32_16x16x32_bf16(a, bp[(size_t)(ctb + 3) * 8 * 64], acc3, 0, 0, 0);
    }
    __syncthreads();   // Abuf dead; preLN aliases it
    int prow = rt * 16 + ((lane >> 4) << 2);
    int c0 = ctb * 16 + (lane & 15);
    float b0 = bl[c0], b1 = bl[c0 + 16], b2 = bl[c0 + 32], b3 = bl[c0 + 48];
#pragma unroll
    for (int q = 0; q < 4; ++q) {
      preLN[prow + q][c0]      = acc0[q] + b0;
      preLN[prow + q][c0 + 16] = acc1[q] + b1;
      preLN[prow + q][c0 + 32] = acc2[q] + b2;
      preLN[prow + q][c0 + 48] = acc3[q] + b3;
    }
  }
  __syncthreads();
  {
    int rr = t >> 3, j = t & 7;
    float s = 0.f, sq = 0.f;
#pragma unroll
    for (int i = 0; i < 16; ++i) { float v = preLN[rr][j + 8 * i]; s += v; sq += v * v; }
    s += __shfl_xor(s, 1); sq += __shfl_xor(sq, 1);
    s += __shfl_xor(s, 2); sq += __shfl_xor(sq, 2);
    s += __shfl_xor(s, 4); sq += __shfl_xor(sq, 4);
    if (j == 0) {
      float mu = s * (1.0f / CC);
      float var = sq * (1.0f / CC) - mu * mu;
      stat[rr][0] = mu;
      stat[rr][1] = rsqrtf(var + 1e-5f);
    }
  }
  __syncthreads();
  if (!FUSE) {
    for (int i = t; i < 32 * CC; i += 256) {
      int r = i >> 7, c = i & 127;
      float v = (preLN[r][c] - stat[r][0]) * stat[r][1] * g[c] + be[c];
      xh[(size_t)(row0 + r) * CC + c] = fmaxf(v, 0.f);
    }
  } else {
    float vx[16];
    int cx = t & 127, rb0 = t >> 7;
    float gc = g[cx], bec = be[cx];
#pragma unroll
    for (int k = 0; k < 16; ++k) {
      int r = rb0 + 2 * k;
      float v = (preLN[r][cx] - stat[r][0]) * stat[r][1] * gc + bec;
      vx[k] = fmaxf(v, 0.f);
    }
    __syncthreads();   // all preLN reads done; Abuf reusable
    {
      int chunkx = cx >> 3;
      int bofs = (cx & 7) * 2;
#pragma unroll
      for (int k = 0; k < 16; ++k) {
        int r = rb0 + 2 * k;
        *reinterpret_cast<unsigned short*>(Abuf + r * 512 + ((chunkx ^ (r & 7)) * 16) + bofs) = f2bf(vx[k]);
      }
    }
    for (int i = t; i < 32 * 32; i += 256) {
      int r = i >> 5, cp = i & 31;
      unsigned pv = *reinterpret_cast<const unsigned*>(&pel2[(size_t)(row0 + r) * PDM + cp * 2]);
      int chunk = 16 + ((cp >> 2) ^ (r & 7));
      *reinterpret_cast<unsigned*>(Abuf + r * 512 + chunk * 16 + (cp & 3) * 4) = pv;
    }
    __syncthreads();
    f32x4 acc0 = {0.f, 0.f, 0.f, 0.f}, acc1 = acc0, acc2 = acc0, acc3 = acc0;
    const char* abase = Abuf + arow * 512;
    const bf16x8* bp0 = reinterpret_cast<const bf16x8*>(Bp2);
    for (int kk = 0; kk < 6; ++kk) {
      bf16x8 a = *reinterpret_cast<const bf16x8*>(abase + (((kk * 4 + (lane >> 4)) ^ axor) * 16));
      const bf16x8* bp = bp0 + (size_t)kk * 64 + lane;
      acc0 = __builtin_amdgcn_mfma_f32_16x16x32_bf16(a, bp[(size_t)(ctb + 0) * 6 * 64], acc0, 0, 0, 0);
      acc1 = __builtin_amdgcn_mfma_f32_16x16x32_bf16(a, bp[(size_t)(ctb + 1) * 6 * 64], acc1, 0, 0, 0);
      acc2 = __builtin_amdgcn_mfma_f32_16x16x32_bf16(a, bp[(size_t)(ctb + 2) * 6 * 64], acc2, 0, 0, 0);
      acc3 = __builtin_amdgcn_mfma_f32_16x16x32_bf16(a, bp[(size_t)(ctb + 3) * 6 * 64], acc3, 0, 0, 0);
    }
    int prow0 = row0 + rt * 16 + ((lane >> 4) << 2);
    int c0 = ctb * 16 + (lane & 15);
    float b0 = bias2[c0], b1 = bias2[c0 + 16], b2 = bias2[c0 + 32], b3 = bias2[c0 + 48];
#pragma unroll
    for (int q = 0; q < 4; ++q) {
      size_t rb = (size_t)(prow0 + q) * CC;
      y_out[rb + c0]      = f2bf(acc0[q] + b0);
      y_out[rb + c0 + 16] = f2bf(acc1[q] + b1);
      y_out[rb + c0 + 32] = f2bf(acc2[q] + b2);
      y_out[rb + c0 + 48] = f2bf(acc3[q] + b3);
    }
  }
}

extern "C" void kernel_launch(void* const* d_in, const int* in_sizes, int n_in,
                              void* d_out, int out_size, void* d_ws, size_t ws_size,
                              hipStream_t stream) {
  const float* x_user = (const float*)d_in[0];
  const float* x_item = (const float*)d_in[1];
  const float* PE     = (const float*)d_in[2];
  const float* sui_Wl = (const float*)d_in[3];
  const float* sui_bl = (const float*)d_in[4];
  const float* sui_Wr = (const float*)d_in[5];
  const float* siu_Wl = (const float*)d_in[6];
  const float* siu_bl = (const float*)d_in[7];
  const float* siu_Wr = (const float*)d_in[8];
  const float* lnu_g  = (const float*)d_in[9];
  const float* lnu_b  = (const float*)d_in[10];
  const float* lni_g  = (const float*)d_in[11];
  const float* lni_b  = (const float*)d_in[12];
  const float* phi_eps = (const float*)d_in[13];
  const float* phi_W1  = (const float*)d_in[14];
  const float* phi_b1  = (const float*)d_in[15];
  const float* phi_W2  = (const float*)d_in[16];
  const float* phi_b2  = (const float*)d_in[17];
  const float* pe_W    = (const float*)d_in[18];
  const float* pe_b    = (const float*)d_in[19];
  const int* edge_ui   = (const int*)d_in[20];
  const int* edge_iu   = (const int*)d_in[21];
  const int* edge_hom  = (const int*)d_in[22];

  float* xh = (float*)d_out;                                    // [NH][C] f32 (final)
  unsigned short* y0    = (unsigned short*)d_ws;                // [NH][C]
  unsigned short* y1    = y0 + (size_t)NHN * CC;                // [NH][C]
  unsigned short* pel0  = y1 + (size_t)NHN * CC;                // [NH][PD]
  unsigned short* pel1  = pel0 + (size_t)NHN * PDM;             // [NH][PD]
  unsigned short* pe_bf = pel1 + (size_t)NHN * PDM;             // [NH][PD]
  int* ip = (int*)(pe_bf + (size_t)NHN * PDM);
  int* cnt      = ip;             ip += NHN;
  int* cnt_hom  = ip;             ip += NHN;
  int* cur_u    = ip;             ip += NUQ;
  int* cur_i    = ip;             ip += NIQ;
  int* cur_h    = ip;             ip += NHN;
  int* off_iu   = ip;             ip += NUQ + 1;
  int* off_ui   = ip;             ip += NIQ + 1;
  int* off_hom  = ip;             ip += NHN + 1;
  int* idx_ui   = ip;             ip += EHET;
  int* idx_iu   = ip;             ip += EHET;
  int* idx_hom  = ip;             ip += EHOM;
  int* blksum   = ip;             ip += 3 * 256;
  int* blkoff   = ip;             ip += 3 * 257;
  unsigned short* packs = (unsigned short*)((((size_t)(ip)) + 15) & ~(size_t)15);
  unsigned short* sageP = packs;                    // [L][2 types] x 32768
  unsigned short* peP   = sageP + 4 * 32768;        // [L] x 24576
  unsigned short* g1P   = peP + 2 * 24576;          // [L] x 8192
  unsigned short* g2P   = g1P + 2 * 8192;           // [L] x 8192

  (void)hipMemsetAsync(cnt, 0, (size_t)(2 * NHN + NUQ + NIQ + NHN) * sizeof(int), stream);

  // fused: histogram (2M atomics) + PE->bf16 stream (6.4M elems)
  k_setup2<<<(2 * EHET + EHOM + NHN * PDM / 2 + 255) / 256, 256, 0, stream>>>(
      edge_ui + EHET, edge_iu + EHET, edge_hom + EHOM, PE, (unsigned*)pe_bf, cnt, cnt_hom);

  k_scan1f<<<NB0 + NB1 + NB2, 256, 0, stream>>>(cnt, cnt_hom, off_iu, off_ui, off_hom, blksum);
  k_scan2f<<<3, 256, 0, stream>>>(blksum, blkoff);
  k_scan3f<<<2 * G0 + G2, 256, 0, stream>>>(off_iu, off_ui, off_hom, blkoff);

  // fused: CSR fill (3 graphs) + weight prepack (14 segments)
  k_fillpack<<<FILLB + 14 * 96, 256, 0, stream>>>(
      edge_ui, edge_iu, edge_hom, off_ui, off_iu, off_hom,
      cur_i, cur_u, cur_h, idx_ui, idx_iu, idx_hom,
      siu_Wl, siu_Wr, sui_Wl, sui_Wr, pe_W, phi_W1, phi_W2,
      sageP, peP, g1P, g2P);

  k_gin2<<<NHN / 32, 256, 0, stream>>>(PE, off_hom, idx_hom, pe_bf,
                                       g1P, phi_b1, g2P, phi_b2, phi_eps, pel0, pel1);
  k_peproj_mfma<<<NHN / 32, 256, 0, stream>>>(x_user, x_item, pel0, peP, pe_b, y0);

  // layer 0: SAGE + LN + ReLU + fused layer-1 peproj -> y1 (no xh round-trip)
  k_sage_mfma<true><<<NHN / 32, 256, 0, stream>>>(y0,
      off_iu, idx_iu, off_ui, idx_ui, cnt,
      sageP + (size_t)0 * 32768, sageP + (size_t)1 * 32768,
      siu_bl, sui_bl, lnu_g, lnu_b, lni_g, lni_b,
      pel1, peP + 24576, pe_b + CC, y1, nullptr);

  // layer 1: SAGE + LN + ReLU -> xh (final f32 output)
  k_sage_mfma<false><<<NHN / 32, 256, 0, stream>>>(y1,
      off_iu, idx_iu, off_ui, idx_ui, cnt,
      sageP + (size_t)2 * 32768, sageP + (size_t)3 * 32768,
      siu_bl + CC, sui_bl + CC,
      lnu_g + CC, lnu_b + CC, lni_g + CC, lni_b + CC,
      nullptr, nullptr, nullptr, nullptr, xh);
}